// Round 14
// baseline (281.533 us; speedup 1.0000x reference)
//
#include <hip/hip_runtime.h>
#include <math.h>

#define L_SEQ   2048
#define DMODEL  512
#define NHEADS  8
#define DK      64
#define DFF     2048
#define BATCH   4
#define NTOP    40
#define MROWS   (BATCH*L_SEQ)   // 8192
#define NCH     8               // kv chunks in attn
#define CHSZ    256             // kv rows per chunk
#define QPAD    48              // 40 padded to 3x16

typedef _Float16 f16;
typedef __attribute__((ext_vector_type(8))) _Float16 f16x8;
typedef __attribute__((ext_vector_type(8))) short    s16x8;
typedef __attribute__((ext_vector_type(4))) float    f32x4;

__device__ __forceinline__ ushort f2h_bits(float x) {
    f16 h = (f16)x;
    return __builtin_bit_cast(ushort, h);
}
__device__ __forceinline__ float h2f(ushort u) {
    return (float)__builtin_bit_cast(f16, u);
}

// fast exact-GELU via A&S 7.1.26 erf poly (|eps|<=1.5e-7); v_rcp instead of div
__device__ __forceinline__ float gelu_f(float v) {
    const float x = fabsf(v) * 0.70710678118654752f;
    const float t = __builtin_amdgcn_rcpf(fmaf(0.3275911f, x, 1.f));
    float p = fmaf(1.061405429f, t, -1.453152027f);
    p = fmaf(p, t, 1.421413741f);
    p = fmaf(p, t, -0.284496736f);
    p = fmaf(p, t, 0.254829592f);
    p *= t;
    const float e = __expf(-x * x);
    const float erfv = copysignf(fmaf(-p, e, 1.f), v);
    return 0.5f * v * (1.f + erfv);
}

#define GLL16(gp, lp) \
    __builtin_amdgcn_global_load_lds((const __attribute__((address_space(1))) void*)(gp), \
                                     (__attribute__((address_space(3))) void*)(lp), 16, 0, 0)

// counted-vmcnt barrier pair (T4): newest 4 loads stay in flight across barrier
#define WAIT_VM4_BAR()  do { asm volatile("s_waitcnt vmcnt(4)" ::: "memory"); \
                             __builtin_amdgcn_s_barrier();                    \
                             asm volatile("" ::: "memory"); } while (0)
#define WAIT_VM0_BAR()  do { asm volatile("s_waitcnt vmcnt(0)" ::: "memory"); \
                             __builtin_amdgcn_s_barrier();                    \
                             asm volatile("" ::: "memory"); } while (0)

// ================= fused QKV GEMM: 64x128 tile, grid (n=4, m=128, z=3) = 1536 blocks
// (r12-r13: 128x128 tile = 768 blocks = 2.7/CU, occupancy-capped at 25%; this
//  halves BM for 6 blocks/CU TLP. LDS 24KB, acc 32 VGPR.)
// z=0: Q = x @ Wq^T + bq  (split3, fp32)
// z=1: K = x @ Wk^T + bk  (split3, fp32 + f16)
// z=2: V = x @ Wv^T + bv  (f16, transposed per-head [bh][d][i])
__global__ __launch_bounds__(256)
void gemm_qkv(const ushort* __restrict__ xh, const ushort* __restrict__ xl,
              const ushort* __restrict__ wqh, const ushort* __restrict__ wql,
              const ushort* __restrict__ wkh, const ushort* __restrict__ wkl,
              const ushort* __restrict__ wvh,
              const float* __restrict__ bq, const float* __restrict__ bk,
              const float* __restrict__ bv,
              float* __restrict__ qo, float* __restrict__ kf,
              ushort* __restrict__ k16, ushort* __restrict__ vt16)
{
    __shared__ __align__(16) ushort sAh[64*32];    // 4 KB
    __shared__ __align__(16) ushort sBh[128*32];   // 8 KB
    __shared__ __align__(16) ushort sAl[64*32];
    __shared__ __align__(16) ushort sBl[128*32];

    const int z = blockIdx.z;
    const int m0 = blockIdx.y * 64;
    const int n0 = blockIdx.x * 128;
    const bool s3 = (z < 2);
    const ushort* Wh = (z == 0) ? wqh : (z == 1) ? wkh : wvh;
    const ushort* Wl = (z == 0) ? wql : wkl;
    const float*  bias = (z == 0) ? bq : (z == 1) ? bk : bv;
    const int K = DMODEL, N = DMODEL;

    const int tid  = threadIdx.x;
    const int wid  = tid >> 6, lane = tid & 63;
    const int wr   = (wid >> 1) * 32;      // wave row origin (0 or 32)
    const int wc   = (wid & 1) * 64;       // wave col origin (0 or 64)
    const int lr   = lane & 15;
    const int ko   = (lane >> 4) * 8;

    f32x4 acc[2][4];
#pragma unroll
    for (int i = 0; i < 2; ++i)
#pragma unroll
        for (int j = 0; j < 4; ++j) acc[i][j] = (f32x4){0.f, 0.f, 0.f, 0.f};

    const int sr = tid >> 2, sc = (tid & 3) * 8;   // sr 0..63
    const size_t gA = (size_t)(m0 + sr) * K + sc;
    const size_t gB = (size_t)(n0 + sr) * K + sc;
    const int l0 = tid * 8, l1 = tid * 8 + 2048;

    for (int k0 = 0; k0 < K; k0 += 32) {
        GLL16(xh + gA + k0,                sAh + l0);
        GLL16(Wh + gB + k0,                sBh + l0);
        GLL16(Wh + gB + (size_t)64*K + k0, sBh + l1);
        if (s3) {
            GLL16(xl + gA + k0,                sAl + l0);
            GLL16(Wl + gB + k0,                sBl + l0);
            GLL16(Wl + gB + (size_t)64*K + k0, sBl + l1);
        }
        __syncthreads();

        f16x8 ah[2], bh[4], al[2], bl[4];
#pragma unroll
        for (int i = 0; i < 2; ++i) {
            ah[i] = *(const f16x8*)&sAh[(wr + i*16 + lr) * 32 + ko];
            if (s3) al[i] = *(const f16x8*)&sAl[(wr + i*16 + lr) * 32 + ko];
        }
#pragma unroll
        for (int j = 0; j < 4; ++j) {
            bh[j] = *(const f16x8*)&sBh[(wc + j*16 + lr) * 32 + ko];
            if (s3) bl[j] = *(const f16x8*)&sBl[(wc + j*16 + lr) * 32 + ko];
        }
#pragma unroll
        for (int i = 0; i < 2; ++i)
#pragma unroll
            for (int j = 0; j < 4; ++j) {
                acc[i][j] = __builtin_amdgcn_mfma_f32_16x16x32_f16(ah[i], bh[j], acc[i][j], 0, 0, 0);
                if (s3) {
                    acc[i][j] = __builtin_amdgcn_mfma_f32_16x16x32_f16(ah[i], bl[j], acc[i][j], 0, 0, 0);
                    acc[i][j] = __builtin_amdgcn_mfma_f32_16x16x32_f16(al[i], bh[j], acc[i][j], 0, 0, 0);
                }
            }
        __syncthreads();
    }

    const int r0 = m0 + wr + (lane >> 4) * 4;
#pragma unroll
    for (int i = 0; i < 2; ++i)
#pragma unroll
        for (int j = 0; j < 4; ++j) {
            const int col = n0 + wc + j * 16 + lr;
            const float bb = bias[col];
#pragma unroll
            for (int qq = 0; qq < 4; ++qq) {
                const int row = r0 + i * 16 + qq;
                const float vv = acc[i][j][qq] + bb;
                if (z == 0) {
                    qo[(size_t)row * N + col] = vv;
                } else if (z == 1) {
                    kf [(size_t)row * N + col] = vv;
                    k16[(size_t)row * N + col] = f2h_bits(vv);
                } else {
                    vt16[((size_t)(row >> 11) * 512 + (col >> 6) * 64 + (col & 63)) * 2048 + (row & 2047)] = f2h_bits(vv);
                }
            }
        }
}

// ================= generic f16 MFMA GEMM (W1): TRI-buffered, counted vmcnt(4)
template<int ACT>
__global__ __launch_bounds__(256)
void gemm16(const ushort* __restrict__ Ah, const ushort* __restrict__ Wh,
            const float* __restrict__ bias, ushort* __restrict__ C16,
            int M, int N, int K)
{
    __shared__ __align__(16) ushort sA[3][128*32];
    __shared__ __align__(16) ushort sB[3][128*32];

    const int m0 = blockIdx.y * 128;
    const int n0 = blockIdx.x * 128;

    const int tid  = threadIdx.x;
    const int wid  = tid >> 6, lane = tid & 63;
    const int wr   = (wid >> 1) * 64;
    const int wc   = (wid & 1) * 64;
    const int lr   = lane & 15;
    const int ko   = (lane >> 4) * 8;

    f32x4 acc[4][4];
#pragma unroll
    for (int i = 0; i < 4; ++i)
#pragma unroll
        for (int j = 0; j < 4; ++j) acc[i][j] = (f32x4){0.f, 0.f, 0.f, 0.f};

    const int sr = tid >> 2, sc = (tid & 3) * 8;
    const size_t gA = (size_t)(m0 + sr) * K + sc;
    const size_t gB = (size_t)(n0 + sr) * K + sc;
    const int l0 = tid * 8, l1 = tid * 8 + 2048;

#define STAGE_G16(buf, kk) do {                                  \
        GLL16(Ah + gA + (kk),                sA[buf] + l0);      \
        GLL16(Ah + gA + (size_t)64*K + (kk), sA[buf] + l1);      \
        GLL16(Wh + gB + (kk),                sB[buf] + l0);      \
        GLL16(Wh + gB + (size_t)64*K + (kk), sB[buf] + l1);      \
    } while (0)

    const int nt = K >> 5;
    STAGE_G16(0, 0);
    STAGE_G16(1, 32);
    WAIT_VM4_BAR();

    int cur = 0;
    for (int t = 0; t < nt; ++t) {
        const int nx = (cur >= 1) ? cur - 1 : cur + 2;
        if (t + 2 < nt) STAGE_G16(nx, (t + 2) << 5);

        const ushort* A_ = sA[cur];
        const ushort* B_ = sB[cur];
        f16x8 ah[4], bh[4];
#pragma unroll
        for (int i = 0; i < 4; ++i) {
            ah[i] = *(const f16x8*)&A_[(wr + i*16 + lr) * 32 + ko];
            bh[i] = *(const f16x8*)&B_[(wc + i*16 + lr) * 32 + ko];
        }
#pragma unroll
        for (int i = 0; i < 4; ++i)
#pragma unroll
            for (int j = 0; j < 4; ++j)
                acc[i][j] = __builtin_amdgcn_mfma_f32_16x16x32_f16(ah[i], bh[j], acc[i][j], 0, 0, 0);

        if (t + 2 < nt) WAIT_VM4_BAR();
        else            WAIT_VM0_BAR();
        cur = (cur >= 2) ? 0 : cur + 1;
    }
#undef STAGE_G16

    const int r0 = m0 + wr + (lane >> 4) * 4;
#pragma unroll
    for (int i = 0; i < 4; ++i)
#pragma unroll
        for (int j = 0; j < 4; ++j) {
            const int col = n0 + wc + j * 16 + lr;
            const float bb = bias[col];
#pragma unroll
            for (int qq = 0; qq < 4; ++qq) {
                const int row = r0 + i * 16 + qq;
                float vv = acc[i][j][qq] + bb;
                if (ACT == 1) vv = gelu_f(vv);
                C16[(size_t)row * N + col] = f2h_bits(vv);
            }
        }
}

// ================= split-K GEMM: TRI-buffered, counted vmcnt(4); f16 partials
// (summed in ln2), NO bias. N = DMODEL fixed.
__global__ __launch_bounds__(256)
void gemm_sk(const ushort* __restrict__ Ah, const ushort* __restrict__ Wh,
             ushort* __restrict__ P0, ushort* __restrict__ P1, int K)
{
    __shared__ __align__(16) ushort sA[3][128*32];
    __shared__ __align__(16) ushort sB[3][128*32];

    const int z = blockIdx.z;
    const int m0 = blockIdx.y * 128;
    const int n0 = blockIdx.x * 128;
    const int khalf = K >> 1, kbase = z * khalf;
    const int N = DMODEL;
    ushort* __restrict__ P = z ? P1 : P0;

    const int tid  = threadIdx.x;
    const int wid  = tid >> 6, lane = tid & 63;
    const int wr   = (wid >> 1) * 64;
    const int wc   = (wid & 1) * 64;
    const int lr   = lane & 15;
    const int ko   = (lane >> 4) * 8;

    f32x4 acc[4][4];
#pragma unroll
    for (int i = 0; i < 4; ++i)
#pragma unroll
        for (int j = 0; j < 4; ++j) acc[i][j] = (f32x4){0.f, 0.f, 0.f, 0.f};

    const int sr = tid >> 2, sc = (tid & 3) * 8;
    const size_t gA = (size_t)(m0 + sr) * K + sc;
    const size_t gB = (size_t)(n0 + sr) * K + sc;
    const int l0 = tid * 8, l1 = tid * 8 + 2048;

#define STAGE_SK(buf, kk) do {                                   \
        GLL16(Ah + gA + (kk),                sA[buf] + l0);      \
        GLL16(Ah + gA + (size_t)64*K + (kk), sA[buf] + l1);      \
        GLL16(Wh + gB + (kk),                sB[buf] + l0);      \
        GLL16(Wh + gB + (size_t)64*K + (kk), sB[buf] + l1);      \
    } while (0)

    const int nt = khalf >> 5;
    STAGE_SK(0, kbase);
    STAGE_SK(1, kbase + 32);
    WAIT_VM4_BAR();

    int cur = 0;
    for (int t = 0; t < nt; ++t) {
        const int nx = (cur >= 1) ? cur - 1 : cur + 2;
        if (t + 2 < nt) STAGE_SK(nx, kbase + ((t + 2) << 5));

        const ushort* A_ = sA[cur];
        const ushort* B_ = sB[cur];
        f16x8 ah[4], bh[4];
#pragma unroll
        for (int i = 0; i < 4; ++i) {
            ah[i] = *(const f16x8*)&A_[(wr + i*16 + lr) * 32 + ko];
            bh[i] = *(const f16x8*)&B_[(wc + i*16 + lr) * 32 + ko];
        }
#pragma unroll
        for (int i = 0; i < 4; ++i)
#pragma unroll
            for (int j = 0; j < 4; ++j)
                acc[i][j] = __builtin_amdgcn_mfma_f32_16x16x32_f16(ah[i], bh[j], acc[i][j], 0, 0, 0);

        if (t + 2 < nt) WAIT_VM4_BAR();
        else            WAIT_VM0_BAR();
        cur = (cur >= 2) ? 0 : cur + 1;
    }
#undef STAGE_SK

    const int r0 = m0 + wr + (lane >> 4) * 4;
#pragma unroll
    for (int i = 0; i < 4; ++i)
#pragma unroll
        for (int j = 0; j < 4; ++j) {
            const int col = n0 + wc + j * 16 + lr;
#pragma unroll
            for (int qq = 0; qq < 4; ++qq) {
                const int row = r0 + i * 16 + qq;
                P[(size_t)row * N + col] = f2h_bits(acc[i][j][qq]);
            }
        }
}

// ================= converts (fused split_x + conv_weights)
__device__ __forceinline__ void split8(const float* __restrict__ s,
                                       ushort* __restrict__ hi, ushort* __restrict__ lo)
{
    s16x8 h8, l8;
#pragma unroll
    for (int j = 0; j < 8; ++j) {
        float x = s[j];
        f16 hh = (f16)x;
        float r = x - (float)hh;
        f16 ll = (f16)r;
        h8[j] = (short)__builtin_bit_cast(ushort, hh);
        l8[j] = (short)__builtin_bit_cast(ushort, ll);
    }
    *(s16x8*)hi = h8;
    *(s16x8*)lo = l8;
}
__device__ __forceinline__ void cvt8(const float* __restrict__ s, ushort* __restrict__ d)
{
    s16x8 h8;
#pragma unroll
    for (int j = 0; j < 8; ++j) h8[j] = (short)f2h_bits(s[j]);
    *(s16x8*)d = h8;
}

__global__ __launch_bounds__(256)
void prep(const float* __restrict__ x,
          const float* __restrict__ Wq, const float* __restrict__ Wk,
          const float* __restrict__ Wv, const float* __restrict__ Wo,
          const float* __restrict__ W1, const float* __restrict__ W2,
          ushort* xh, ushort* xl,
          ushort* wqh, ushort* wql, ushort* wkh, ushort* wkl,
          ushort* wvh, ushort* woh, ushort* w1h, ushort* w2h)
{
    const int bid = blockIdx.x;
    if (bid < 2048) {
        const int t = bid * 256 + threadIdx.x;
        split8(x + (size_t)t * 8, xh + (size_t)t * 8, xl + (size_t)t * 8);
        return;
    }
    const int t = (bid - 2048) * 256 + threadIdx.x;
    const int e = t * 8;
    const int S = DMODEL * DMODEL;
    if      (e < S)           split8(Wq + e,           wqh + e,           wql + e);
    else if (e < 2*S)         split8(Wk + (e -   S),   wkh + (e -   S),   wkl + (e -   S));
    else if (e < 3*S)         cvt8  (Wv + (e - 2*S),   wvh + (e - 2*S));
    else if (e < 4*S)         cvt8  (Wo + (e - 3*S),   woh + (e - 3*S));
    else if (e < 4*S + DFF*DMODEL) cvt8(W1 + (e - 4*S), w1h + (e - 4*S));
    else                      cvt8  (W2 + (e - 4*S - DFF*DMODEL), w2h + (e - 4*S - DFF*DMODEL));
}

// ================= sampled scores + M statistic — coalesced gather
__global__ __launch_bounds__(256, 4)
void sample_scores(const float* __restrict__ q, const float* __restrict__ k,
                   const int* __restrict__ idxs, float* __restrict__ Mout)
{
    __shared__ float4 qs[4][128];

    const int bid = blockIdx.x;                 // 2048
    const int xcd = bid & 7;
    const int b   = xcd >> 1;
    const int chunk = (bid >> 3) * 2 + (xcd & 1);
    const int wid = threadIdx.x >> 6, lane = threadIdx.x & 63;
    const int i = chunk * 4 + wid;
    const int jsub = lane >> 3, c = lane & 7;

    {
        const float4* qrow = (const float4*)&q[((size_t)(b * L_SEQ + i)) * DMODEL];
        qs[wid][lane]      = qrow[lane];
        qs[wid][lane + 64] = qrow[lane + 64];
    }
    __syncthreads();

    const float4* kb = (const float4*)&k[(size_t)b * L_SEQ * DMODEL];

    float mx = -1e30f, sm = 0.f;
#pragma unroll
    for (int jb = 0; jb < 5; ++jb) {
        const int kidx = idxs[i * NTOP + jb * 8 + jsub];
        const float4* krow = kb + (size_t)kidx * (DMODEL / 4);
        float hacc[8];
#pragma unroll
        for (int u = 0; u < 8; ++u) hacc[u] = 0.f;
#pragma unroll
        for (int t = 0; t < 16; ++t) {
            const int p = t * 8 + c;
            const float4 kv = krow[p];
            const float4 qv = qs[wid][p];
            float d = 0.f;
            d = fmaf(qv.x, kv.x, d);
            d = fmaf(qv.y, kv.y, d);
            d = fmaf(qv.z, kv.z, d);
            d = fmaf(qv.w, kv.w, d);
            hacc[t >> 1] += d;
        }
#pragma unroll
        for (int s = 1; s < 8; s <<= 1)
#pragma unroll
            for (int u = 0; u < 8; ++u) hacc[u] += __shfl_xor(hacc[u], s);
        float sel = hacc[0];
#pragma unroll
        for (int u = 1; u < 8; ++u) sel = (c == u) ? hacc[u] : sel;
        mx = fmaxf(mx, sel);
        sm += sel;
    }
#pragma unroll
    for (int s = 8; s < 64; s <<= 1) {
        mx = fmaxf(mx, __shfl_xor(mx, s));
        sm += __shfl_xor(sm, s);
    }
    if (jsub == 0)
        Mout[((size_t)(b * NHEADS + c)) * L_SEQ + i] = mx - sm * (1.0f / (float)L_SEQ);
}

// ================= top-40 per (b,h)
__global__ __launch_bounds__(256)
void topk40(const float* __restrict__ Mstat, int* __restrict__ top_idx)
{
    const int bh = blockIdx.x;
    __shared__ float vals[L_SEQ];
    __shared__ float wv[4];
    __shared__ int   wi[4];
    const int tid = threadIdx.x;
    const int lane = tid & 63, wid = tid >> 6;
    for (int t = tid; t < L_SEQ; t += 256) vals[t] = Mstat[(size_t)bh * L_SEQ + t];
    __syncthreads();

    for (int n = 0; n < NTOP; ++n) {
        float bv = -1e30f; int bi = L_SEQ;
#pragma unroll
        for (int r = 0; r < 8; ++r) {
            const int t = tid + r * 256;
            float vvv = vals[t];
            if (vvv > bv) { bv = vvv; bi = t; }
        }
#pragma unroll
        for (int s = 32; s > 0; s >>= 1) {
            float ov = __shfl_xor(bv, s); int oi = __shfl_xor(bi, s);
            if (ov > bv || (ov == bv && oi < bi)) { bv = ov; bi = oi; }
        }
        if (lane == 0) { wv[wid] = bv; wi[wid] = bi; }
        __syncthreads();
        if (tid == 0) {
            float fb = wv[0]; int fi = wi[0];
#pragma unroll
            for (int w = 1; w < 4; ++w)
                if (wv[w] > fb || (wv[w] == fb && wi[w] < fi)) { fb = wv[w]; fi = wi[w]; }
            top_idx[bh * NTOP + n] = fi;
            vals[fi] = -1e30f;
        }
        __syncthreads();
    }
}

// ================= mean of V per (b,h): reads transposed Vt rows coalesced
__global__ __launch_bounds__(256)
void vmean_kernel(const ushort* __restrict__ vt, float* __restrict__ vmean)
{
    const int bh = blockIdx.x;
    const int wid = threadIdx.x >> 6, lane = threadIdx.x & 63;
#pragma unroll
    for (int dd = 0; dd < 16; ++dd) {
        const int d = wid * 16 + dd;
        const ushort* row = vt + ((size_t)bh * 64 + d) * 2048;
        float s = 0.f;
#pragma unroll
        for (int it = 0; it < 4; ++it) {
            s16x8 vv = *(const s16x8*)&row[it * 512 + lane * 8];
#pragma unroll
            for (int j = 0; j < 8; ++j) s += h2f((ushort)vv[j]);
        }
#pragma unroll
        for (int st = 1; st < 64; st <<= 1) s += __shfl_xor(s, st);
        if (lane == 0) vmean[bh * DK + d] = s * (1.0f / (float)L_SEQ);
    }
}

// ================= fill ctx (f16) with per-(b,h) mean-of-V
__global__ __launch_bounds__(256)
void fill_ctx(const float* __restrict__ vmean, ushort* __restrict__ ctx)
{
    const int t = blockIdx.x * 256 + threadIdx.x;
    const int e = t * 8;
    const int col = e & (DMODEL - 1);
    const int row = e >> 9;
    const int b = row >> 11;
    const int h = col >> 6, d = col & 63;
    const float* vm = &vmean[(b * 8 + h) * DK + d];
    s16x8 o;
#pragma unroll
    for (int j = 0; j < 8; ++j) o[j] = (short)f2h_bits(vm[j]);
    *(s16x8*)&ctx[e] = o;
}

// ================= MFMA flash attention over selected rows
__global__ __launch_bounds__(256, 1)
void attn_flash(const float* __restrict__ q, const ushort* __restrict__ k16,
                const ushort* __restrict__ vt16, const int* __restrict__ top_idx,
                float* __restrict__ part_o, float* __restrict__ part_ml)
{
    __shared__ __align__(16) ushort K_lds [CHSZ * 64];
    __shared__ __align__(16) ushort Vt_lds[64 * CHSZ];
    __shared__ __align__(16) ushort Q_lds [QPAD * 64];
    __shared__ __align__(16) ushort P_lds [QPAD * CHSZ];
    __shared__ float red_max[4][QPAD];
    __shared__ float red_sum[4][QPAD];

    const int bh = blockIdx.x >> 3, ch = blockIdx.x & 7;
    const int b = bh >> 3, h = bh & 7;
    const int tid = threadIdx.x;
    const int wid = tid >> 6, lane = tid & 63;
    const int lr = lane & 15, ks = lane >> 4;

    {
        const ushort* kbase = k16 + ((size_t)b * L_SEQ + ch * CHSZ) * DMODEL + h * DK;
#pragma unroll
        for (int it = 0; it < 8; ++it) {
            const int qi2 = wid * 8 + it;
            const int row = qi2 * 8 + (lane >> 3);
            const int g = (lane & 7) ^ (row & 7);
            GLL16(kbase + (size_t)row * DMODEL + g * 8, K_lds + qi2 * 512 + lane * 8);
        }
        const ushort* vtb = vt16 + ((size_t)bh * 64) * 2048 + ch * CHSZ;
#pragma unroll
        for (int it = 0; it < 8; ++it) {
            const int qi2 = wid * 8 + it;
            const int drow = qi2 * 2 + (lane >> 5);
            const int g = (lane & 31) ^ (drow & 7);
            GLL16(vtb + (size_t)drow * 2048 + g * 8, Vt_lds + qi2 * 512 + lane * 8);
        }
    }
    if (tid < QPAD * 4) {
        const int r = tid >> 2, part = tid & 3;
        s16x8 w0, w1;
        if (r < NTOP) {
            const int qi = top_idx[bh * NTOP + r];
            const float* qp = q + ((size_t)b * L_SEQ + qi) * DMODEL + h * DK + part * 16;
#pragma unroll
            for (int u = 0; u < 8; ++u) { w0[u] = (short)f2h_bits(qp[u]); w1[u] = (short)f2h_bits(qp[u + 8]); }
        } else {
#pragma unroll
            for (int u = 0; u < 8; ++u) { w0[u] = 0; w1[u] = 0; }
        }
        const int g0 = part * 2;
        *(s16x8*)((char*)Q_lds + r * 128 + (((g0    ) ^ (r & 7)) << 4)) = w0;
        *(s16x8*)((char*)Q_lds + r * 128 + (((g0 + 1) ^ (r & 7)) << 4)) = w1;
    }
    __syncthreads();

    f16x8 af[3][2], bf[4][2];
#pragma unroll
    for (int i = 0; i < 3; ++i)
#pragma unroll
        for (int kt = 0; kt < 2; ++kt) {
            const int row = i * 16 + lr;
            const int g = (kt * 4 + ks) ^ (row & 7);
            af[i][kt] = *(const f16x8*)((const char*)Q_lds + row * 128 + g * 16);
        }
#pragma unroll
    for (int j = 0; j < 4; ++j)
#pragma unroll
        for (int kt = 0; kt < 2; ++kt) {
            const int row = wid * 64 + j * 16 + lr;
            const int g = (kt * 4 + ks) ^ (row & 7);
            bf[j][kt] = *(const f16x8*)((const char*)K_lds + row * 128 + g * 16);
        }
    f32x4 acc[3][4];
#pragma unroll
    for (int i = 0; i < 3; ++i)
#pragma unroll
        for (int j = 0; j < 4; ++j) acc[i][j] = (f32x4){0.f, 0.f, 0.f, 0.f};
#pragma unroll
    for (int i = 0; i < 3; ++i)
#pragma unroll
        for (int j = 0; j < 4; ++j)
#pragma unroll
            for (int kt = 0; kt < 2; ++kt)
                acc[i][j] = __builtin_amdgcn_mfma_f32_16x16x32_f16(af[i][kt], bf[j][kt], acc[i][j], 0, 0, 0);

    float mrow[3][4];
#pragma unroll
    for (int i = 0; i < 3; ++i)
#pragma unroll
        for (int r = 0; r < 4; ++r) {
            float m = acc[i][0][r];
            m = fmaxf(m, acc[i][1][r]); m = fmaxf(m, acc[i][2][r]); m = fmaxf(m, acc[i][3][r]);
            mrow[i][r] = m;
        }
#pragma unroll
    for (int s = 1; s < 16; s <<= 1)
#pragma unroll
        for (int i = 0; i < 3; ++i)
#pragma unroll
            for (int r = 0; r < 4; ++r) mrow[i][r] = fmaxf(mrow[i][r], __shfl_xor(mrow[i][r], s));
    if (lr == 0)
#pragma unroll
        for (int i = 0; i < 3; ++i)
#pragma unroll
            for (int r = 0; r < 4; ++r) red_max[wid][i * 16 + ks * 4 + r] = mrow[i][r];
    __syncthreads();
    float mc[3][4];
#pragma unroll
    for (int i = 0; i < 3; ++i)
#pragma unroll
        for (int r = 0; r < 4; ++r) {
            const int row = i * 16 + ks * 4 + r;
            mc[i][r] = fmaxf(fmaxf(red_max[0][row], red_max[1][row]),
                             fmaxf(red_max[2][row], red_max[3][row]));
        }

    float srow[3][4];
#pragma unroll
    for (int i = 0; i < 3; ++i)
#pragma unroll
        for (int r = 0; r < 4; ++r) srow[i][r] = 0.f;
#pragma unroll
    for (int i = 0; i < 3; ++i)
#pragma unroll
        for (int j = 0; j < 4; ++j)
#pragma unroll
            for (int r = 0; r < 4; ++r) {
                const float p = expf(acc[i][j][r] - mc[i][r]);
                srow[i][r] += p;
                const int row = i * 16 + ks * 4 + r;
                const int cc = wid * 64 + j * 16 + lr;
                const int g = (cc >> 3) ^ (row & 7);
                *(ushort*)((char*)P_lds + row * 512 + g * 16 + (cc & 7) * 2) = f2h_bits(p);
            }
#pragma unroll
    for (int s = 1; s < 16; s <<= 1)
#pragma unroll
        for (int i = 0; i < 3; ++i)
#pragma unroll
            for (int r = 0; r < 4; ++r) srow[i][r] += __shfl_xor(srow[i][r], s);
    if (lr == 0)
#pragma unroll
        for (int i = 0; i < 3; ++i)
#pragma unroll
            for (int r = 0; r < 4; ++r) red_sum[wid][i * 16 + ks * 4 + r] = srow[i][r];
    __syncthreads();

    if (wid == 0 && lr == 0) {
#pragma unroll
        for (int i = 0; i < 3; ++i)
#pragma unroll
            for (int r = 0; r < 4; ++r) {
                const int row = i * 16 + ks * 4 + r;
                const float lc = red_sum[0][row] + red_sum[1][row] + red_sum[2][row] + red_sum[3][row];
                part_ml[(((size_t)bh * NCH + ch) * QPAD + row) * 2 + 0] = mc[i][r];
                part_ml[(((size_t)bh * NCH + ch) * QPAD + row) * 2 + 1] = lc;
            }
    }

    f32x4 acc2[3];
#pragma unroll
    for (int i = 0; i < 3; ++i) acc2[i] = (f32x4){0.f, 0.f, 0.f, 0.f};
#pragma unroll
    for (int kt = 0; kt < 8; ++kt) {
        f16x8 vb;
        {
            const int row = wid * 16 + lr;
            const int g = (kt * 4 + ks) ^ (row & 7);
            vb = *(const f16x8*)((const char*)Vt_lds + row * 512 + g * 16);
        }
#pragma unroll
        for (int i = 0; i < 3; ++i) {
            const int row = i * 16 + lr;
            const int g = (kt * 4 + ks) ^ (row & 7);
            const f16x8 pa = *(const f16x8*)((const char*)P_lds + row * 512 + g * 16);
            acc2[i] = __builtin_amdgcn_mfma_f32_16x16x32_f16(pa, vb, acc2[i], 0, 0, 0);
        }
    }
#pragma unroll
    for (int i = 0; i < 3; ++i)
#pragma unroll
        for (int r = 0; r < 4; ++r) {
            const int row = i * 16 + ks * 4 + r;
            const int d = wid * 16 + lr;
            part_o[((((size_t)bh * NCH + ch) * QPAD) + row) * 64 + d] = acc2[i][r];
        }
}

// ================= flash combine
__global__ __launch_bounds__(256)
void attn_combine(const float* __restrict__ part_o, const float* __restrict__ part_ml,
                  const int* __restrict__ top_idx, ushort* __restrict__ ctx)
{
    const int bh = blockIdx.x;
    const int b = bh >> 3, h = bh & 7;
    const int d = threadIdx.x & 63, qg = threadIdx.x >> 6;
#pragma unroll
    for (int u = 0; u < 10; ++u) {
        const int qq = qg * 10 + u;
        float mv[NCH], lv[NCH];
        float m = -1e30f;
#pragma unroll
        for (int c = 0; c < NCH; ++c) {
            mv[c] = part_ml[(((size_t)bh * NCH + c) * QPAD + qq) * 2 + 0];
            lv[c] = part_ml[(((size_t)bh * NCH + c) * QPAD + qq) * 2 + 1];
            m = fmaxf(m, mv[c]);
        }
        float l = 0.f, o = 0.f;
#pragma unroll
        for (int c = 0; c < NCH; ++c) {
            const float e = expf(mv[c] - m);
            l += e * lv[c];
            o += e * part_o[((((size_t)bh * NCH + c) * QPAD) + qq) * 64 + d];
        }
        const int qi = top_idx[bh * NTOP + qq];
        ctx[((size_t)b * L_SEQ + qi) * DMODEL + h * DK + d] = f2h_bits(o / l);
    }
}

// ================= LayerNorm(a + h2f(p0) + h2f(p1) + bias) * g + be; optional f16 copy
template<int W16>
__global__ __launch_bounds__(256)
void ln2(const float* __restrict__ a, const ushort* __restrict__ p0,
         const ushort* __restrict__ p1, const float* __restrict__ bias,
         const float* __restrict__ g, const float* __restrict__ be,
         float* __restrict__ out, ushort* __restrict__ out16)
{
    const int row = blockIdx.x; const int tid = threadIdx.x;
    const size_t base = (size_t)row * DMODEL;
    float x0 = a[base + tid]       + h2f(p0[base + tid])       + h2f(p1[base + tid])       + bias[tid];
    float x1 = a[base + 256 + tid] + h2f(p0[base + 256 + tid]) + h2f(p1[base + 256 + tid]) + bias[256 + tid];

    __shared__ float red[256];
    red[tid] = x0 + x1; __syncthreads();
    for (int st = 128; st > 0; st >>= 1) { if (tid < st) red[tid] += red[tid + st]; __syncthreads(); }
    const float mu = red[0] * (1.0f / (float)DMODEL);
    __syncthreads();

    const float d0 = x0 - mu, d1 = x1 - mu;
    red[tid] = d0 * d0 + d1 * d1; __syncthreads();
    for (int st = 128; st > 0; st >>= 1) { if (tid < st) red[tid] += red[tid + st]; __syncthreads(); }
    const float var = red[0] * (1.0f / (float)DMODEL);
    const float rstd = 1.0f / sqrtf(var + 1e-5f);

    const float y0 = d0 * rstd * g[tid]       + be[tid];
    const float y1 = d1 * rstd * g[256 + tid] + be[256 + tid];
    out[base + tid]       = y0;
    out[base + 256 + tid] = y1;
    if (W16) {
        out16[base + tid]       = f2h_bits(y0);
        out16[base + 256 + tid] = f2h_bits(y1);
    }
}

// ================= launch
extern "C" void kernel_launch(void* const* d_in, const int* in_sizes, int n_in,
                              void* d_out, int out_size, void* d_ws, size_t ws_size,
                              hipStream_t stream)
{
    const float* x    = (const float*)d_in[0];
    const int*   idxs = (const int*)  d_in[1];
    const float* Wq = (const float*)d_in[2];  const float* bq = (const float*)d_in[3];
    const float* Wk = (const float*)d_in[4];  const float* bk = (const float*)d_in[5];
    const float* Wv = (const float*)d_in[6];  const float* bv = (const float*)d_in[7];
    const float* Wo = (const float*)d_in[8];  const float* bo = (const float*)d_in[9];
    const float* W1 = (const float*)d_in[10]; const float* b1 = (const float*)d_in[11];
    const float* W2 = (const float*)d_in[12]; const float* b2 = (const float*)d_in[13];
    const float* g1 = (const float*)d_in[14]; const float* be1= (const float*)d_in[15];
    const float* g2 = (const float*)d_in[16]; const float* be2= (const float*)d_in[17];

    const size_t MD = (size_t)MROWS * DMODEL;      // byte-unit = 4 MB
    char* W = (char*)d_ws;
    ushort* xh    = (ushort*)(W);                  // [0,2)   dead after gemm_qkv
    ushort* xl    = (ushort*)(W + 2*MD);           // [2,4)   dead after gemm_qkv
    float*  q     = (float*) (W + 4*MD);           // [4,8)   dead after attn_flash
    float*  k     = (float*) (W + 8*MD);           // [8,12)  dead after sample_scores
    ushort* k16   = (ushort*)(W + 12*MD);          // [12,14) dead after attn_flash
    ushort* vt16  = (ushort*)(W + 14*MD);          // [14,16) dead after attn_flash
    ushort* ctx16 = (ushort*)(W + 16*MD);          // [16,18) dead after Wo
    ushort* wo_p0 = (ushort*)(W);                  // [0,4)   (f16, uses half)
    ushort* wo_p1 = (ushort*)(W + 4*MD);           // [4,8)
    float*  h1    = (float*) (W + 8*MD);           // [8,12)  overlays k (dead)
    ushort* h116  = (ushort*)(W + 12*MD);          // [12,14) overlays k16 (dead)
    ushort* mid16 = (ushort*)(W);                  // [0,8)   overlays wo parts (dead after LN1)
    ushort* w2_p0 = (ushort*)(W + 12*MD);          // [12,16) overlays h116/vt16 (dead after W1)
    ushort* w2_p1 = (ushort*)(W + 16*MD);          // [16,20) overlays ctx16 (dead)
    ushort* wqh   = (ushort*)(W + 20*MD);
    ushort* wql  = wqh + DMODEL*DMODEL;
    ushort* wkh  = wql + DMODEL*DMODEL;
    ushort* wkl  = wkh + DMODEL*DMODEL;
    ushort* wvh  = wkl + DMODEL*DMODEL;
    ushort* woh  = wvh + DMODEL*DMODEL;
    ushort* w1h  = woh + DMODEL*DMODEL;
    ushort* w2h  = w1h + DFF*DMODEL;
    float*  Mstat = (float*)(w2h + DMODEL*DFF);
    float*  vmean = Mstat + (size_t)BATCH * NHEADS * L_SEQ;
    int*    top_idx = (int*)(vmean + BATCH * NHEADS * DK);
    float*  part_o  = (float*)(top_idx + BATCH * NHEADS * NTOP);
    float*  part_ml = part_o + (size_t)BATCH * NHEADS * NCH * QPAD * 64;

    dim3 blk(256);

    prep<<<dim3(2048 + 1536), blk, 0, stream>>>(x, Wq, Wk, Wv, Wo, W1, W2,
                                                xh, xl, wqh, wql, wkh, wkl, wvh, woh, w1h, w2h);

    gemm_qkv<<<dim3(DMODEL/128, MROWS/64, 3), blk, 0, stream>>>(
        xh, xl, wqh, wql, wkh, wkl, wvh, bq, bk, bv, q, k, k16, vt16);

    sample_scores<<<dim3(2048), blk, 0, stream>>>(q, k, idxs, Mstat);
    topk40<<<dim3(BATCH*NHEADS), blk, 0, stream>>>(Mstat, top_idx);
    vmean_kernel<<<dim3(BATCH*NHEADS), blk, 0, stream>>>(vt16, vmean);
    fill_ctx<<<dim3(MD/2048), blk, 0, stream>>>(vmean, ctx16);
    attn_flash<<<dim3(BATCH*NHEADS*NCH), blk, 0, stream>>>(q, k16, vt16, top_idx, part_o, part_ml);
    attn_combine<<<dim3(BATCH*NHEADS), blk, 0, stream>>>(part_o, part_ml, top_idx, ctx16);

    // Wo split-K=2 (bias folded into LN1; f16 partials)
    gemm_sk<<<dim3(DMODEL/128, MROWS/128, 2), blk, 0, stream>>>(ctx16, woh, wo_p0, wo_p1, DMODEL);
    ln2<1><<<dim3(MROWS), blk, 0, stream>>>(x, wo_p0, wo_p1, bo, g1, be1, h1, h116);

    // FFN
    gemm16<1><<<dim3(DFF/128, MROWS/128), blk, 0, stream>>>(h116, w1h, b1, mid16, MROWS, DFF, DMODEL);
    gemm_sk<<<dim3(DMODEL/128, MROWS/128, 2), blk, 0, stream>>>(mid16, w2h, w2_p0, w2_p1, DFF);
    ln2<0><<<dim3(MROWS), blk, 0, stream>>>(h1, w2_p0, w2_p1, b2, g2, be2, (float*)d_out, nullptr);
}

// Round 15
// 270.968 us; speedup vs baseline: 1.0390x; 1.0390x over previous
//
#include <hip/hip_runtime.h>
#include <math.h>

#define L_SEQ   2048
#define DMODEL  512
#define NHEADS  8
#define DK      64
#define DFF     2048
#define BATCH   4
#define NTOP    40
#define MROWS   (BATCH*L_SEQ)   // 8192
#define NCH     8               // kv chunks in attn
#define CHSZ    256             // kv rows per chunk
#define QPAD    48              // 40 padded to 3x16

typedef _Float16 f16;
typedef __attribute__((ext_vector_type(8))) _Float16 f16x8;
typedef __attribute__((ext_vector_type(8))) short    s16x8;
typedef __attribute__((ext_vector_type(4))) float    f32x4;

__device__ __forceinline__ ushort f2h_bits(float x) {
    f16 h = (f16)x;
    return __builtin_bit_cast(ushort, h);
}
__device__ __forceinline__ float h2f(ushort u) {
    return (float)__builtin_bit_cast(f16, u);
}

// fast exact-GELU via A&S 7.1.26 erf poly (|eps|<=1.5e-7); v_rcp instead of div
__device__ __forceinline__ float gelu_f(float v) {
    const float x = fabsf(v) * 0.70710678118654752f;
    const float t = __builtin_amdgcn_rcpf(fmaf(0.3275911f, x, 1.f));
    float p = fmaf(1.061405429f, t, -1.453152027f);
    p = fmaf(p, t, 1.421413741f);
    p = fmaf(p, t, -0.284496736f);
    p = fmaf(p, t, 0.254829592f);
    p *= t;
    const float e = __expf(-x * x);
    const float erfv = copysignf(fmaf(-p, e, 1.f), v);
    return 0.5f * v * (1.f + erfv);
}

#define GLL16(gp, lp) \
    __builtin_amdgcn_global_load_lds((const __attribute__((address_space(1))) void*)(gp), \
                                     (__attribute__((address_space(3))) void*)(lp), 16, 0, 0)

// ================= fused QKV GEMM: grid (n=4, m=64, z=3)  [128x128, single-buffer:
// 32KB LDS, 3 blocks/CU. MEASURED LEDGER: dbuf 64KB -> 2/CU = 66us (r11 WORSE);
// BM=64 -> 6/CU but 54us (r14 WORSE, FETCH +81%); this config = 43.5us BEST (r12).]
// z=0: Q = x @ Wq^T + bq  (split3, fp32)
// z=1: K = x @ Wk^T + bk  (split3, fp32 + f16)
// z=2: V = x @ Wv^T + bv  (f16, transposed per-head [bh][d][i])
__global__ __launch_bounds__(256)
void gemm_qkv(const ushort* __restrict__ xh, const ushort* __restrict__ xl,
              const ushort* __restrict__ wqh, const ushort* __restrict__ wql,
              const ushort* __restrict__ wkh, const ushort* __restrict__ wkl,
              const ushort* __restrict__ wvh,
              const float* __restrict__ bq, const float* __restrict__ bk,
              const float* __restrict__ bv,
              float* __restrict__ qo, float* __restrict__ kf,
              ushort* __restrict__ k16, ushort* __restrict__ vt16)
{
    __shared__ __align__(16) ushort sAh[128*32];
    __shared__ __align__(16) ushort sBh[128*32];
    __shared__ __align__(16) ushort sAl[128*32];
    __shared__ __align__(16) ushort sBl[128*32];

    const int z = blockIdx.z;
    const int m0 = blockIdx.y * 128;
    const int n0 = blockIdx.x * 128;
    const bool s3 = (z < 2);
    const ushort* Wh = (z == 0) ? wqh : (z == 1) ? wkh : wvh;
    const ushort* Wl = (z == 0) ? wql : wkl;
    const float*  bias = (z == 0) ? bq : (z == 1) ? bk : bv;
    const int K = DMODEL, N = DMODEL;

    const int tid  = threadIdx.x;
    const int wid  = tid >> 6, lane = tid & 63;
    const int wr   = (wid >> 1) * 64;
    const int wc   = (wid & 1) * 64;
    const int lr   = lane & 15;
    const int ko   = (lane >> 4) * 8;

    f32x4 acc[4][4];
#pragma unroll
    for (int i = 0; i < 4; ++i)
#pragma unroll
        for (int j = 0; j < 4; ++j) acc[i][j] = (f32x4){0.f, 0.f, 0.f, 0.f};

    const int sr = tid >> 2, sc = (tid & 3) * 8;
    const size_t gA = (size_t)(m0 + sr) * K + sc;
    const size_t gB = (size_t)(n0 + sr) * K + sc;
    const int l0 = tid * 8, l1 = tid * 8 + 2048;

    for (int k0 = 0; k0 < K; k0 += 32) {
        GLL16(xh + gA + k0,                sAh + l0);
        GLL16(xh + gA + (size_t)64*K + k0, sAh + l1);
        GLL16(Wh + gB + k0,                sBh + l0);
        GLL16(Wh + gB + (size_t)64*K + k0, sBh + l1);
        if (s3) {
            GLL16(xl + gA + k0,                sAl + l0);
            GLL16(xl + gA + (size_t)64*K + k0, sAl + l1);
            GLL16(Wl + gB + k0,                sBl + l0);
            GLL16(Wl + gB + (size_t)64*K + k0, sBl + l1);
        }
        __syncthreads();

        f16x8 ah[4], bh[4], al[4], bl[4];
#pragma unroll
        for (int i = 0; i < 4; ++i) {
            ah[i] = *(const f16x8*)&sAh[(wr + i*16 + lr) * 32 + ko];
            bh[i] = *(const f16x8*)&sBh[(wc + i*16 + lr) * 32 + ko];
            if (s3) {
                al[i] = *(const f16x8*)&sAl[(wr + i*16 + lr) * 32 + ko];
                bl[i] = *(const f16x8*)&sBl[(wc + i*16 + lr) * 32 + ko];
            }
        }
#pragma unroll
        for (int i = 0; i < 4; ++i)
#pragma unroll
            for (int j = 0; j < 4; ++j) {
                acc[i][j] = __builtin_amdgcn_mfma_f32_16x16x32_f16(ah[i], bh[j], acc[i][j], 0, 0, 0);
                if (s3) {
                    acc[i][j] = __builtin_amdgcn_mfma_f32_16x16x32_f16(ah[i], bl[j], acc[i][j], 0, 0, 0);
                    acc[i][j] = __builtin_amdgcn_mfma_f32_16x16x32_f16(al[i], bh[j], acc[i][j], 0, 0, 0);
                }
            }
        __syncthreads();
    }

    const int r0 = m0 + wr + (lane >> 4) * 4;
#pragma unroll
    for (int i = 0; i < 4; ++i)
#pragma unroll
        for (int j = 0; j < 4; ++j) {
            const int col = n0 + wc + j * 16 + lr;
            const float bb = bias[col];
#pragma unroll
            for (int qq = 0; qq < 4; ++qq) {
                const int row = r0 + i * 16 + qq;
                const float vv = acc[i][j][qq] + bb;
                if (z == 0) {
                    qo[(size_t)row * N + col] = vv;
                } else if (z == 1) {
                    kf [(size_t)row * N + col] = vv;
                    k16[(size_t)row * N + col] = f2h_bits(vv);
                } else {
                    vt16[((size_t)(row >> 11) * 512 + (col >> 6) * 64 + (col & 63)) * 2048 + (row & 2047)] = f2h_bits(vv);
                }
            }
        }
}

// ================= generic f16 MFMA GEMM (W1): stage-ahead double-buffered K-loop
template<int ACT>
__global__ __launch_bounds__(256)
void gemm16(const ushort* __restrict__ Ah, const ushort* __restrict__ Wh,
            const float* __restrict__ bias, ushort* __restrict__ C16,
            int M, int N, int K)
{
    __shared__ __align__(16) ushort sA[2][128*32];
    __shared__ __align__(16) ushort sB[2][128*32];

    const int m0 = blockIdx.y * 128;
    const int n0 = blockIdx.x * 128;

    const int tid  = threadIdx.x;
    const int wid  = tid >> 6, lane = tid & 63;
    const int wr   = (wid >> 1) * 64;
    const int wc   = (wid & 1) * 64;
    const int lr   = lane & 15;
    const int ko   = (lane >> 4) * 8;

    f32x4 acc[4][4];
#pragma unroll
    for (int i = 0; i < 4; ++i)
#pragma unroll
        for (int j = 0; j < 4; ++j) acc[i][j] = (f32x4){0.f, 0.f, 0.f, 0.f};

    const int sr = tid >> 2, sc = (tid & 3) * 8;
    const size_t gA = (size_t)(m0 + sr) * K + sc;
    const size_t gB = (size_t)(n0 + sr) * K + sc;
    const int l0 = tid * 8, l1 = tid * 8 + 2048;

    GLL16(Ah + gA,                sA[0] + l0);
    GLL16(Ah + gA + (size_t)64*K, sA[0] + l1);
    GLL16(Wh + gB,                sB[0] + l0);
    GLL16(Wh + gB + (size_t)64*K, sB[0] + l1);
    __syncthreads();

    const int nt = K >> 5;
    int cur = 0;
    for (int t = 0; t < nt; ++t) {
        if (t + 1 < nt) {
            const int k1 = (t + 1) << 5;
            GLL16(Ah + gA + k1,                sA[cur ^ 1] + l0);
            GLL16(Ah + gA + (size_t)64*K + k1, sA[cur ^ 1] + l1);
            GLL16(Wh + gB + k1,                sB[cur ^ 1] + l0);
            GLL16(Wh + gB + (size_t)64*K + k1, sB[cur ^ 1] + l1);
        }
        const ushort* A_ = sA[cur];
        const ushort* B_ = sB[cur];
        f16x8 ah[4], bh[4];
#pragma unroll
        for (int i = 0; i < 4; ++i) {
            ah[i] = *(const f16x8*)&A_[(wr + i*16 + lr) * 32 + ko];
            bh[i] = *(const f16x8*)&B_[(wc + i*16 + lr) * 32 + ko];
        }
#pragma unroll
        for (int i = 0; i < 4; ++i)
#pragma unroll
            for (int j = 0; j < 4; ++j)
                acc[i][j] = __builtin_amdgcn_mfma_f32_16x16x32_f16(ah[i], bh[j], acc[i][j], 0, 0, 0);
        __syncthreads();
        cur ^= 1;
    }

    const int r0 = m0 + wr + (lane >> 4) * 4;
#pragma unroll
    for (int i = 0; i < 4; ++i)
#pragma unroll
        for (int j = 0; j < 4; ++j) {
            const int col = n0 + wc + j * 16 + lr;
            const float bb = bias[col];
#pragma unroll
            for (int qq = 0; qq < 4; ++qq) {
                const int row = r0 + i * 16 + qq;
                float vv = acc[i][j][qq] + bb;
                if (ACT == 1) vv = gelu_f(vv);
                C16[(size_t)row * N + col] = f2h_bits(vv);
            }
        }
}

// ================= split-K GEMM: stage-ahead dbuf; f16 partials (summed in ln2),
// NO bias. N = DMODEL fixed.
__global__ __launch_bounds__(256)
void gemm_sk(const ushort* __restrict__ Ah, const ushort* __restrict__ Wh,
             ushort* __restrict__ P0, ushort* __restrict__ P1, int K)
{
    __shared__ __align__(16) ushort sA[2][128*32];
    __shared__ __align__(16) ushort sB[2][128*32];

    const int z = blockIdx.z;
    const int m0 = blockIdx.y * 128;
    const int n0 = blockIdx.x * 128;
    const int khalf = K >> 1, kbase = z * khalf;
    const int N = DMODEL;
    ushort* __restrict__ P = z ? P1 : P0;

    const int tid  = threadIdx.x;
    const int wid  = tid >> 6, lane = tid & 63;
    const int wr   = (wid >> 1) * 64;
    const int wc   = (wid & 1) * 64;
    const int lr   = lane & 15;
    const int ko   = (lane >> 4) * 8;

    f32x4 acc[4][4];
#pragma unroll
    for (int i = 0; i < 4; ++i)
#pragma unroll
        for (int j = 0; j < 4; ++j) acc[i][j] = (f32x4){0.f, 0.f, 0.f, 0.f};

    const int sr = tid >> 2, sc = (tid & 3) * 8;
    const size_t gA = (size_t)(m0 + sr) * K + sc;
    const size_t gB = (size_t)(n0 + sr) * K + sc;
    const int l0 = tid * 8, l1 = tid * 8 + 2048;

    GLL16(Ah + gA + kbase,                sA[0] + l0);
    GLL16(Ah + gA + (size_t)64*K + kbase, sA[0] + l1);
    GLL16(Wh + gB + kbase,                sB[0] + l0);
    GLL16(Wh + gB + (size_t)64*K + kbase, sB[0] + l1);
    __syncthreads();

    const int nt = khalf >> 5;
    int cur = 0;
    for (int t = 0; t < nt; ++t) {
        if (t + 1 < nt) {
            const int k1 = kbase + ((t + 1) << 5);
            GLL16(Ah + gA + k1,                sA[cur ^ 1] + l0);
            GLL16(Ah + gA + (size_t)64*K + k1, sA[cur ^ 1] + l1);
            GLL16(Wh + gB + k1,                sB[cur ^ 1] + l0);
            GLL16(Wh + gB + (size_t)64*K + k1, sB[cur ^ 1] + l1);
        }
        const ushort* A_ = sA[cur];
        const ushort* B_ = sB[cur];
        f16x8 ah[4], bh[4];
#pragma unroll
        for (int i = 0; i < 4; ++i) {
            ah[i] = *(const f16x8*)&A_[(wr + i*16 + lr) * 32 + ko];
            bh[i] = *(const f16x8*)&B_[(wc + i*16 + lr) * 32 + ko];
        }
#pragma unroll
        for (int i = 0; i < 4; ++i)
#pragma unroll
            for (int j = 0; j < 4; ++j)
                acc[i][j] = __builtin_amdgcn_mfma_f32_16x16x32_f16(ah[i], bh[j], acc[i][j], 0, 0, 0);
        __syncthreads();
        cur ^= 1;
    }

    const int r0 = m0 + wr + (lane >> 4) * 4;
#pragma unroll
    for (int i = 0; i < 4; ++i)
#pragma unroll
        for (int j = 0; j < 4; ++j) {
            const int col = n0 + wc + j * 16 + lr;
#pragma unroll
            for (int qq = 0; qq < 4; ++qq) {
                const int row = r0 + i * 16 + qq;
                P[(size_t)row * N + col] = f2h_bits(acc[i][j][qq]);
            }
        }
}

// ================= converts (fused split_x + conv_weights)
__device__ __forceinline__ void split8(const float* __restrict__ s,
                                       ushort* __restrict__ hi, ushort* __restrict__ lo)
{
    s16x8 h8, l8;
#pragma unroll
    for (int j = 0; j < 8; ++j) {
        float x = s[j];
        f16 hh = (f16)x;
        float r = x - (float)hh;
        f16 ll = (f16)r;
        h8[j] = (short)__builtin_bit_cast(ushort, hh);
        l8[j] = (short)__builtin_bit_cast(ushort, ll);
    }
    *(s16x8*)hi = h8;
    *(s16x8*)lo = l8;
}
__device__ __forceinline__ void cvt8(const float* __restrict__ s, ushort* __restrict__ d)
{
    s16x8 h8;
#pragma unroll
    for (int j = 0; j < 8; ++j) h8[j] = (short)f2h_bits(s[j]);
    *(s16x8*)d = h8;
}

__global__ __launch_bounds__(256)
void prep(const float* __restrict__ x,
          const float* __restrict__ Wq, const float* __restrict__ Wk,
          const float* __restrict__ Wv, const float* __restrict__ Wo,
          const float* __restrict__ W1, const float* __restrict__ W2,
          ushort* xh, ushort* xl,
          ushort* wqh, ushort* wql, ushort* wkh, ushort* wkl,
          ushort* wvh, ushort* woh, ushort* w1h, ushort* w2h)
{
    const int bid = blockIdx.x;
    if (bid < 2048) {
        const int t = bid * 256 + threadIdx.x;
        split8(x + (size_t)t * 8, xh + (size_t)t * 8, xl + (size_t)t * 8);
        return;
    }
    const int t = (bid - 2048) * 256 + threadIdx.x;
    const int e = t * 8;
    const int S = DMODEL * DMODEL;
    if      (e < S)           split8(Wq + e,           wqh + e,           wql + e);
    else if (e < 2*S)         split8(Wk + (e -   S),   wkh + (e -   S),   wkl + (e -   S));
    else if (e < 3*S)         cvt8  (Wv + (e - 2*S),   wvh + (e - 2*S));
    else if (e < 4*S)         cvt8  (Wo + (e - 3*S),   woh + (e - 3*S));
    else if (e < 4*S + DFF*DMODEL) cvt8(W1 + (e - 4*S), w1h + (e - 4*S));
    else                      cvt8  (W2 + (e - 4*S - DFF*DMODEL), w2h + (e - 4*S - DFF*DMODEL));
}

// ================= sampled scores + M statistic — coalesced gather
__global__ __launch_bounds__(256, 4)
void sample_scores(const float* __restrict__ q, const float* __restrict__ k,
                   const int* __restrict__ idxs, float* __restrict__ Mout)
{
    __shared__ float4 qs[4][128];

    const int bid = blockIdx.x;                 // 2048
    const int xcd = bid & 7;
    const int b   = xcd >> 1;
    const int chunk = (bid >> 3) * 2 + (xcd & 1);
    const int wid = threadIdx.x >> 6, lane = threadIdx.x & 63;
    const int i = chunk * 4 + wid;
    const int jsub = lane >> 3, c = lane & 7;

    {
        const float4* qrow = (const float4*)&q[((size_t)(b * L_SEQ + i)) * DMODEL];
        qs[wid][lane]      = qrow[lane];
        qs[wid][lane + 64] = qrow[lane + 64];
    }
    __syncthreads();

    const float4* kb = (const float4*)&k[(size_t)b * L_SEQ * DMODEL];

    float mx = -1e30f, sm = 0.f;
#pragma unroll
    for (int jb = 0; jb < 5; ++jb) {
        const int kidx = idxs[i * NTOP + jb * 8 + jsub];
        const float4* krow = kb + (size_t)kidx * (DMODEL / 4);
        float hacc[8];
#pragma unroll
        for (int u = 0; u < 8; ++u) hacc[u] = 0.f;
#pragma unroll
        for (int t = 0; t < 16; ++t) {
            const int p = t * 8 + c;
            const float4 kv = krow[p];
            const float4 qv = qs[wid][p];
            float d = 0.f;
            d = fmaf(qv.x, kv.x, d);
            d = fmaf(qv.y, kv.y, d);
            d = fmaf(qv.z, kv.z, d);
            d = fmaf(qv.w, kv.w, d);
            hacc[t >> 1] += d;
        }
#pragma unroll
        for (int s = 1; s < 8; s <<= 1)
#pragma unroll
            for (int u = 0; u < 8; ++u) hacc[u] += __shfl_xor(hacc[u], s);
        float sel = hacc[0];
#pragma unroll
        for (int u = 1; u < 8; ++u) sel = (c == u) ? hacc[u] : sel;
        mx = fmaxf(mx, sel);
        sm += sel;
    }
#pragma unroll
    for (int s = 8; s < 64; s <<= 1) {
        mx = fmaxf(mx, __shfl_xor(mx, s));
        sm += __shfl_xor(sm, s);
    }
    if (jsub == 0)
        Mout[((size_t)(b * NHEADS + c)) * L_SEQ + i] = mx - sm * (1.0f / (float)L_SEQ);
}

// ================= top-40 per (b,h)
__global__ __launch_bounds__(256)
void topk40(const float* __restrict__ Mstat, int* __restrict__ top_idx)
{
    const int bh = blockIdx.x;
    __shared__ float vals[L_SEQ];
    __shared__ float wv[4];
    __shared__ int   wi[4];
    const int tid = threadIdx.x;
    const int lane = tid & 63, wid = tid >> 6;
    for (int t = tid; t < L_SEQ; t += 256) vals[t] = Mstat[(size_t)bh * L_SEQ + t];
    __syncthreads();

    for (int n = 0; n < NTOP; ++n) {
        float bv = -1e30f; int bi = L_SEQ;
#pragma unroll
        for (int r = 0; r < 8; ++r) {
            const int t = tid + r * 256;
            float vvv = vals[t];
            if (vvv > bv) { bv = vvv; bi = t; }
        }
#pragma unroll
        for (int s = 32; s > 0; s >>= 1) {
            float ov = __shfl_xor(bv, s); int oi = __shfl_xor(bi, s);
            if (ov > bv || (ov == bv && oi < bi)) { bv = ov; bi = oi; }
        }
        if (lane == 0) { wv[wid] = bv; wi[wid] = bi; }
        __syncthreads();
        if (tid == 0) {
            float fb = wv[0]; int fi = wi[0];
#pragma unroll
            for (int w = 1; w < 4; ++w)
                if (wv[w] > fb || (wv[w] == fb && wi[w] < fi)) { fb = wv[w]; fi = wi[w]; }
            top_idx[bh * NTOP + n] = fi;
            vals[fi] = -1e30f;
        }
        __syncthreads();
    }
}

// ================= mean of V per (b,h): reads transposed Vt rows coalesced
__global__ __launch_bounds__(256)
void vmean_kernel(const ushort* __restrict__ vt, float* __restrict__ vmean)
{
    const int bh = blockIdx.x;
    const int wid = threadIdx.x >> 6, lane = threadIdx.x & 63;
#pragma unroll
    for (int dd = 0; dd < 16; ++dd) {
        const int d = wid * 16 + dd;
        const ushort* row = vt + ((size_t)bh * 64 + d) * 2048;
        float s = 0.f;
#pragma unroll
        for (int it = 0; it < 4; ++it) {
            s16x8 vv = *(const s16x8*)&row[it * 512 + lane * 8];
#pragma unroll
            for (int j = 0; j < 8; ++j) s += h2f((ushort)vv[j]);
        }
#pragma unroll
        for (int st = 1; st < 64; st <<= 1) s += __shfl_xor(s, st);
        if (lane == 0) vmean[bh * DK + d] = s * (1.0f / (float)L_SEQ);
    }
}

// ================= fill ctx (f16) with per-(b,h) mean-of-V
__global__ __launch_bounds__(256)
void fill_ctx(const float* __restrict__ vmean, ushort* __restrict__ ctx)
{
    const int t = blockIdx.x * 256 + threadIdx.x;
    const int e = t * 8;
    const int col = e & (DMODEL - 1);
    const int row = e >> 9;
    const int b = row >> 11;
    const int h = col >> 6, d = col & 63;
    const float* vm = &vmean[(b * 8 + h) * DK + d];
    s16x8 o;
#pragma unroll
    for (int j = 0; j < 8; ++j) o[j] = (short)f2h_bits(vm[j]);
    *(s16x8*)&ctx[e] = o;
}

// ================= MFMA flash attention over selected rows
__global__ __launch_bounds__(256, 1)
void attn_flash(const float* __restrict__ q, const ushort* __restrict__ k16,
                const ushort* __restrict__ vt16, const int* __restrict__ top_idx,
                float* __restrict__ part_o, float* __restrict__ part_ml)
{
    __shared__ __align__(16) ushort K_lds [CHSZ * 64];
    __shared__ __align__(16) ushort Vt_lds[64 * CHSZ];
    __shared__ __align__(16) ushort Q_lds [QPAD * 64];
    __shared__ __align__(16) ushort P_lds [QPAD * CHSZ];
    __shared__ float red_max[4][QPAD];
    __shared__ float red_sum[4][QPAD];

    const int bh = blockIdx.x >> 3, ch = blockIdx.x & 7;
    const int b = bh >> 3, h = bh & 7;
    const int tid = threadIdx.x;
    const int wid = tid >> 6, lane = tid & 63;
    const int lr = lane & 15, ks = lane >> 4;

    {
        const ushort* kbase = k16 + ((size_t)b * L_SEQ + ch * CHSZ) * DMODEL + h * DK;
#pragma unroll
        for (int it = 0; it < 8; ++it) {
            const int qi2 = wid * 8 + it;
            const int row = qi2 * 8 + (lane >> 3);
            const int g = (lane & 7) ^ (row & 7);
            GLL16(kbase + (size_t)row * DMODEL + g * 8, K_lds + qi2 * 512 + lane * 8);
        }
        const ushort* vtb = vt16 + ((size_t)bh * 64) * 2048 + ch * CHSZ;
#pragma unroll
        for (int it = 0; it < 8; ++it) {
            const int qi2 = wid * 8 + it;
            const int drow = qi2 * 2 + (lane >> 5);
            const int g = (lane & 31) ^ (drow & 7);
            GLL16(vtb + (size_t)drow * 2048 + g * 8, Vt_lds + qi2 * 512 + lane * 8);
        }
    }
    if (tid < QPAD * 4) {
        const int r = tid >> 2, part = tid & 3;
        s16x8 w0, w1;
        if (r < NTOP) {
            const int qi = top_idx[bh * NTOP + r];
            const float* qp = q + ((size_t)b * L_SEQ + qi) * DMODEL + h * DK + part * 16;
#pragma unroll
            for (int u = 0; u < 8; ++u) { w0[u] = (short)f2h_bits(qp[u]); w1[u] = (short)f2h_bits(qp[u + 8]); }
        } else {
#pragma unroll
            for (int u = 0; u < 8; ++u) { w0[u] = 0; w1[u] = 0; }
        }
        const int g0 = part * 2;
        *(s16x8*)((char*)Q_lds + r * 128 + (((g0    ) ^ (r & 7)) << 4)) = w0;
        *(s16x8*)((char*)Q_lds + r * 128 + (((g0 + 1) ^ (r & 7)) << 4)) = w1;
    }
    __syncthreads();

    f16x8 af[3][2], bf[4][2];
#pragma unroll
    for (int i = 0; i < 3; ++i)
#pragma unroll
        for (int kt = 0; kt < 2; ++kt) {
            const int row = i * 16 + lr;
            const int g = (kt * 4 + ks) ^ (row & 7);
            af[i][kt] = *(const f16x8*)((const char*)Q_lds + row * 128 + g * 16);
        }
#pragma unroll
    for (int j = 0; j < 4; ++j)
#pragma unroll
        for (int kt = 0; kt < 2; ++kt) {
            const int row = wid * 64 + j * 16 + lr;
            const int g = (kt * 4 + ks) ^ (row & 7);
            bf[j][kt] = *(const f16x8*)((const char*)K_lds + row * 128 + g * 16);
        }
    f32x4 acc[3][4];
#pragma unroll
    for (int i = 0; i < 3; ++i)
#pragma unroll
        for (int j = 0; j < 4; ++j) acc[i][j] = (f32x4){0.f, 0.f, 0.f, 0.f};
#pragma unroll
    for (int i = 0; i < 3; ++i)
#pragma unroll
        for (int j = 0; j < 4; ++j)
#pragma unroll
            for (int kt = 0; kt < 2; ++kt)
                acc[i][j] = __builtin_amdgcn_mfma_f32_16x16x32_f16(af[i][kt], bf[j][kt], acc[i][j], 0, 0, 0);

    float mrow[3][4];
#pragma unroll
    for (int i = 0; i < 3; ++i)
#pragma unroll
        for (int r = 0; r < 4; ++r) {
            float m = acc[i][0][r];
            m = fmaxf(m, acc[i][1][r]); m = fmaxf(m, acc[i][2][r]); m = fmaxf(m, acc[i][3][r]);
            mrow[i][r] = m;
        }
#pragma unroll
    for (int s = 1; s < 16; s <<= 1)
#pragma unroll
        for (int i = 0; i < 3; ++i)
#pragma unroll
            for (int r = 0; r < 4; ++r) mrow[i][r] = fmaxf(mrow[i][r], __shfl_xor(mrow[i][r], s));
    if (lr == 0)
#pragma unroll
        for (int i = 0; i < 3; ++i)
#pragma unroll
            for (int r = 0; r < 4; ++r) red_max[wid][i * 16 + ks * 4 + r] = mrow[i][r];
    __syncthreads();
    float mc[3][4];
#pragma unroll
    for (int i = 0; i < 3; ++i)
#pragma unroll
        for (int r = 0; r < 4; ++r) {
            const int row = i * 16 + ks * 4 + r;
            mc[i][r] = fmaxf(fmaxf(red_max[0][row], red_max[1][row]),
                             fmaxf(red_max[2][row], red_max[3][row]));
        }

    float srow[3][4];
#pragma unroll
    for (int i = 0; i < 3; ++i)
#pragma unroll
        for (int r = 0; r < 4; ++r) srow[i][r] = 0.f;
#pragma unroll
    for (int i = 0; i < 3; ++i)
#pragma unroll
        for (int j = 0; j < 4; ++j)
#pragma unroll
            for (int r = 0; r < 4; ++r) {
                const float p = expf(acc[i][j][r] - mc[i][r]);
                srow[i][r] += p;
                const int row = i * 16 + ks * 4 + r;
                const int cc = wid * 64 + j * 16 + lr;
                const int g = (cc >> 3) ^ (row & 7);
                *(ushort*)((char*)P_lds + row * 512 + g * 16 + (cc & 7) * 2) = f2h_bits(p);
            }
#pragma unroll
    for (int s = 1; s < 16; s <<= 1)
#pragma unroll
        for (int i = 0; i < 3; ++i)
#pragma unroll
            for (int r = 0; r < 4; ++r) srow[i][r] += __shfl_xor(srow[i][r], s);
    if (lr == 0)
#pragma unroll
        for (int i = 0; i < 3; ++i)
#pragma unroll
            for (int r = 0; r < 4; ++r) red_sum[wid][i * 16 + ks * 4 + r] = srow[i][r];
    __syncthreads();

    if (wid == 0 && lr == 0) {
#pragma unroll
        for (int i = 0; i < 3; ++i)
#pragma unroll
            for (int r = 0; r < 4; ++r) {
                const int row = i * 16 + ks * 4 + r;
                const float lc = red_sum[0][row] + red_sum[1][row] + red_sum[2][row] + red_sum[3][row];
                part_ml[(((size_t)bh * NCH + ch) * QPAD + row) * 2 + 0] = mc[i][r];
                part_ml[(((size_t)bh * NCH + ch) * QPAD + row) * 2 + 1] = lc;
            }
    }

    f32x4 acc2[3];
#pragma unroll
    for (int i = 0; i < 3; ++i) acc2[i] = (f32x4){0.f, 0.f, 0.f, 0.f};
#pragma unroll
    for (int kt = 0; kt < 8; ++kt) {
        f16x8 vb;
        {
            const int row = wid * 16 + lr;
            const int g = (kt * 4 + ks) ^ (row & 7);
            vb = *(const f16x8*)((const char*)Vt_lds + row * 512 + g * 16);
        }
#pragma unroll
        for (int i = 0; i < 3; ++i) {
            const int row = i * 16 + lr;
            const int g = (kt * 4 + ks) ^ (row & 7);
            const f16x8 pa = *(const f16x8*)((const char*)P_lds + row * 512 + g * 16);
            acc2[i] = __builtin_amdgcn_mfma_f32_16x16x32_f16(pa, vb, acc2[i], 0, 0, 0);
        }
    }
#pragma unroll
    for (int i = 0; i < 3; ++i)
#pragma unroll
        for (int r = 0; r < 4; ++r) {
            const int row = i * 16 + ks * 4 + r;
            const int d = wid * 16 + lr;
            part_o[((((size_t)bh * NCH + ch) * QPAD) + row) * 64 + d] = acc2[i][r];
        }
}

// ================= flash combine
__global__ __launch_bounds__(256)
void attn_combine(const float* __restrict__ part_o, const float* __restrict__ part_ml,
                  const int* __restrict__ top_idx, ushort* __restrict__ ctx)
{
    const int bh = blockIdx.x;
    const int b = bh >> 3, h = bh & 7;
    const int d = threadIdx.x & 63, qg = threadIdx.x >> 6;
#pragma unroll
    for (int u = 0; u < 10; ++u) {
        const int qq = qg * 10 + u;
        float mv[NCH], lv[NCH];
        float m = -1e30f;
#pragma unroll
        for (int c = 0; c < NCH; ++c) {
            mv[c] = part_ml[(((size_t)bh * NCH + c) * QPAD + qq) * 2 + 0];
            lv[c] = part_ml[(((size_t)bh * NCH + c) * QPAD + qq) * 2 + 1];
            m = fmaxf(m, mv[c]);
        }
        float l = 0.f, o = 0.f;
#pragma unroll
        for (int c = 0; c < NCH; ++c) {
            const float e = expf(mv[c] - m);
            l += e * lv[c];
            o += e * part_o[((((size_t)bh * NCH + c) * QPAD) + qq) * 64 + d];
        }
        const int qi = top_idx[bh * NTOP + qq];
        ctx[((size_t)b * L_SEQ + qi) * DMODEL + h * DK + d] = f2h_bits(o / l);
    }
}

// ================= LayerNorm(a + h2f(p0) + h2f(p1) + bias) * g + be; optional f16 copy
template<int W16>
__global__ __launch_bounds__(256)
void ln2(const float* __restrict__ a, const ushort* __restrict__ p0,
         const ushort* __restrict__ p1, const float* __restrict__ bias,
         const float* __restrict__ g, const float* __restrict__ be,
         float* __restrict__ out, ushort* __restrict__ out16)
{
    const int row = blockIdx.x; const int tid = threadIdx.x;
    const size_t base = (size_t)row * DMODEL;
    float x0 = a[base + tid]       + h2f(p0[base + tid])       + h2f(p1[base + tid])       + bias[tid];
    float x1 = a[base + 256 + tid] + h2f(p0[base + 256 + tid]) + h2f(p1[base + 256 + tid]) + bias[256 + tid];

    __shared__ float red[256];
    red[tid] = x0 + x1; __syncthreads();
    for (int st = 128; st > 0; st >>= 1) { if (tid < st) red[tid] += red[tid + st]; __syncthreads(); }
    const float mu = red[0] * (1.0f / (float)DMODEL);
    __syncthreads();

    const float d0 = x0 - mu, d1 = x1 - mu;
    red[tid] = d0 * d0 + d1 * d1; __syncthreads();
    for (int st = 128; st > 0; st >>= 1) { if (tid < st) red[tid] += red[tid + st]; __syncthreads(); }
    const float var = red[0] * (1.0f / (float)DMODEL);
    const float rstd = 1.0f / sqrtf(var + 1e-5f);

    const float y0 = d0 * rstd * g[tid]       + be[tid];
    const float y1 = d1 * rstd * g[256 + tid] + be[256 + tid];
    out[base + tid]       = y0;
    out[base + 256 + tid] = y1;
    if (W16) {
        out16[base + tid]       = f2h_bits(y0);
        out16[base + 256 + tid] = f2h_bits(y1);
    }
}

// ================= launch
extern "C" void kernel_launch(void* const* d_in, const int* in_sizes, int n_in,
                              void* d_out, int out_size, void* d_ws, size_t ws_size,
                              hipStream_t stream)
{
    const float* x    = (const float*)d_in[0];
    const int*   idxs = (const int*)  d_in[1];
    const float* Wq = (const float*)d_in[2];  const float* bq = (const float*)d_in[3];
    const float* Wk = (const float*)d_in[4];  const float* bk = (const float*)d_in[5];
    const float* Wv = (const float*)d_in[6];  const float* bv = (const float*)d_in[7];
    const float* Wo = (const float*)d_in[8];  const float* bo = (const float*)d_in[9];
    const float* W1 = (const float*)d_in[10]; const float* b1 = (const float*)d_in[11];
    const float* W2 = (const float*)d_in[12]; const float* b2 = (const float*)d_in[13];
    const float* g1 = (const float*)d_in[14]; const float* be1= (const float*)d_in[15];
    const float* g2 = (const float*)d_in[16]; const float* be2= (const float*)d_in[17];

    const size_t MD = (size_t)MROWS * DMODEL;      // byte-unit = 4 MB
    char* W = (char*)d_ws;
    ushort* xh    = (ushort*)(W);                  // [0,2)   dead after gemm_qkv
    ushort* xl    = (ushort*)(W + 2*MD);           // [2,4)   dead after gemm_qkv
    float*  q     = (float*) (W + 4*MD);           // [4,8)   dead after attn_flash
    float*  k     = (float*) (W + 8*MD);           // [8,12)  dead after sample_scores
    ushort* k16   = (ushort*)(W + 12*MD);          // [12,14) dead after attn_flash
    ushort* vt16  = (ushort*)(W + 14*MD);          // [14,16) dead after attn_flash
    ushort* ctx16 = (ushort*)(W + 16*MD);          // [16,18) dead after Wo
    ushort* wo_p0 = (ushort*)(W);                  // [0,4)   (f16, uses half)
    ushort* wo_p1 = (ushort*)(W + 4*MD);           // [4,8)
    float*  h1    = (float*) (W + 8*MD);           // [8,12)  overlays k (dead)
    ushort* h116  = (ushort*)(W + 12*MD);          // [12,14) overlays k16 (dead)
    ushort* mid16 = (ushort*)(W);                  // [0,8)   overlays wo parts (dead after LN1)
    ushort* w2_p0 = (ushort*)(W + 12*MD);          // [12,16) overlays h116/vt16 (dead after W1)
    ushort* w2_p1 = (ushort*)(W + 16*MD);          // [16,20) overlays ctx16 (dead)
    ushort* wqh   = (ushort*)(W + 20*MD);
    ushort* wql  = wqh + DMODEL*DMODEL;
    ushort* wkh  = wql + DMODEL*DMODEL;
    ushort* wkl  = wkh + DMODEL*DMODEL;
    ushort* wvh  = wkl + DMODEL*DMODEL;
    ushort* woh  = wvh + DMODEL*DMODEL;
    ushort* w1h  = woh + DMODEL*DMODEL;
    ushort* w2h  = w1h + DFF*DMODEL;
    float*  Mstat = (float*)(w2h + DMODEL*DFF);
    float*  vmean = Mstat + (size_t)BATCH * NHEADS * L_SEQ;
    int*    top_idx = (int*)(vmean + BATCH * NHEADS * DK);
    float*  part_o  = (float*)(top_idx + BATCH * NHEADS * NTOP);
    float*  part_ml = part_o + (size_t)BATCH * NHEADS * NCH * QPAD * 64;

    dim3 blk(256);

    prep<<<dim3(2048 + 1536), blk, 0, stream>>>(x, Wq, Wk, Wv, Wo, W1, W2,
                                                xh, xl, wqh, wql, wkh, wkl, wvh, woh, w1h, w2h);

    gemm_qkv<<<dim3(DMODEL/128, MROWS/128, 3), blk, 0, stream>>>(
        xh, xl, wqh, wql, wkh, wkl, wvh, bq, bk, bv, q, k, k16, vt16);

    sample_scores<<<dim3(2048), blk, 0, stream>>>(q, k, idxs, Mstat);
    topk40<<<dim3(BATCH*NHEADS), blk, 0, stream>>>(Mstat, top_idx);
    vmean_kernel<<<dim3(BATCH*NHEADS), blk, 0, stream>>>(vt16, vmean);
    fill_ctx<<<dim3(MD/2048), blk, 0, stream>>>(vmean, ctx16);
    attn_flash<<<dim3(BATCH*NHEADS*NCH), blk, 0, stream>>>(q, k16, vt16, top_idx, part_o, part_ml);
    attn_combine<<<dim3(BATCH*NHEADS), blk, 0, stream>>>(part_o, part_ml, top_idx, ctx16);

    // Wo split-K=2 (bias folded into LN1; f16 partials)
    gemm_sk<<<dim3(DMODEL/128, MROWS/128, 2), blk, 0, stream>>>(ctx16, woh, wo_p0, wo_p1, DMODEL);
    ln2<1><<<dim3(MROWS), blk, 0, stream>>>(x, wo_p0, wo_p1, bo, g1, be1, h1, h116);

    // FFN
    gemm16<1><<<dim3(DFF/128, MROWS/128), blk, 0, stream>>>(h116, w1h, b1, mid16, MROWS, DFF, DMODEL);
    gemm_sk<<<dim3(DMODEL/128, MROWS/128, 2), blk, 0, stream>>>(mid16, w2h, w2_p0, w2_p1, DFF);
    ln2<0><<<dim3(MROWS), blk, 0, stream>>>(h1, w2_p0, w2_p1, b2, g2, be2, (float*)d_out, nullptr);
}